// Round 8
// baseline (303.853 us; speedup 1.0000x reference)
//
#include <hip/hip_runtime.h>

#define NB 4
#define NS 1024
#define NE 512
#define NH 8
#define ND 64
#define NC 16      // chunks per sequence
#define CSZ 64     // chunk size

static constexpr float FEPS = 1e-6f;

typedef _Float16 half_t;
typedef __attribute__((ext_vector_type(8))) _Float16 f16x8;
typedef __attribute__((ext_vector_type(4))) float f32x4;

__device__ __forceinline__ float h_log2kap(int h) {
  float kap = (1.0f - exp2f(-5.0f - (float)h)) * 0.8f;
  return log2f(kap);
}
__device__ __forceinline__ float silu_f(float x) {
  return x / (1.0f + __expf(-x));
}

// ------ prep: weight convert+transpose (13 mats) + segment scan, one launch --
struct WCArgs {
  const float* src[13];
  half_t* dst;
  const int* dones;
  int* seg;
};
__global__ __launch_bounds__(256) void prep_kernel(WCArgs a) {
  __shared__ half_t T[64][72];  // [k][n] tile, padded
  __shared__ int s[NS];
  const int t = threadIdx.x;
  if (blockIdx.y < 13) {
    const int w = blockIdx.y;
    const int kt = (blockIdx.x & 7) * 64;
    const int nt = (blockIdx.x >> 3) * 64;
    const float* src = a.src[w] + (size_t)kt * NE + nt;
    const int c = t & 63;
    for (int r = t >> 6; r < 64; r += 4) T[r][c] = (half_t)src[(size_t)r * NE + c];
    __syncthreads();
    const int n = t >> 2, kq = (t & 3) * 16;
    half_t* dst = a.dst + (size_t)w * NE * NE + (size_t)(nt + n) * NE + kt + kq;
    f16x8 o0, o1;
#pragma unroll
    for (int j = 0; j < 8; j++) {
      o0[j] = T[kq + j][n];
      o1[j] = T[kq + 8 + j][n];
    }
    *(f16x8*)dst = o0;
    *(f16x8*)(dst + 8) = o1;
  } else {
    if (blockIdx.x >= NB) return;
    const int b = blockIdx.x;
    for (int i = t; i < NS; i += 256) s[i] = (a.dones[b * NS + i] != 0) ? 1 : 0;
    __syncthreads();
    for (int off = 1; off < NS; off <<= 1) {
      int tv[4];
#pragma unroll
      for (int u = 0; u < 4; u++) {
        int i = t + 256 * u;
        tv[u] = s[i] + ((i >= off) ? s[i - off] : 0);
      }
      __syncthreads();
#pragma unroll
      for (int u = 0; u < 4; u++) s[t + 256 * u] = tv[u];
      __syncthreads();
    }
    for (int i = t; i < NS; i += 256) a.seg[b * NS + i] = s[i];
  }
}

// ---------------- fp16 MFMA GEMM: O[w] = f(A[w]) @ Wt[w]^T * alpha[w] --------
// Wt[w]: [n][k] fp16 (pre-transposed). Tile 128 x (64*TN), BK=32, 4 waves.
// amode: 0 = A fp16; 2 = A fp32 (convert in staging); 3 = silu(A)*A2 (fp16)
// omode: 0 = fp32 out; 1 = fp16 out
struct GArgs {
  const void *A0, *A1, *A2i, *A3;
  const void *B0, *B1, *B2, *B3;   // second elementwise operand (amode 3)
  const half_t *W0, *W1, *W2, *W3;
  void *O0, *O1, *O2, *O3;
  float a0, a1, a2, a3;
  int am0, am1, am2, am3;
  int om0, om1, om2, om3;
};

template <int TN>
__global__ __launch_bounds__(256) void mfma_gemm_kernel(GArgs g) {
  constexpr int NT = 64 * TN;
  constexpr int NTILES = NE / NT;
  constexpr int MF = (TN == 2) ? 4 : 2;
  __shared__ half_t As[128 * 32];
  __shared__ half_t Bs[NT * 32];
  const int t = threadIdx.x;
  const int bn = blockIdx.x;
  const int wsel = bn / NTILES;
  const int n0 = (bn % NTILES) * NT;
  const int m0 = blockIdx.y * 128;
  const void* A = wsel == 0 ? g.A0 : wsel == 1 ? g.A1 : wsel == 2 ? g.A2i : g.A3;
  const void* A2 = wsel == 0 ? g.B0 : wsel == 1 ? g.B1 : wsel == 2 ? g.B2 : g.B3;
  const half_t* W = wsel == 0 ? g.W0 : wsel == 1 ? g.W1 : wsel == 2 ? g.W2 : g.W3;
  void* O = wsel == 0 ? g.O0 : wsel == 1 ? g.O1 : wsel == 2 ? g.O2 : g.O3;
  const float alpha = wsel == 0 ? g.a0 : wsel == 1 ? g.a1 : wsel == 2 ? g.a2 : g.a3;
  const int am = wsel == 0 ? g.am0 : wsel == 1 ? g.am1 : wsel == 2 ? g.am2 : g.am3;
  const int om = wsel == 0 ? g.om0 : wsel == 1 ? g.om1 : wsel == 2 ? g.om2 : g.om3;
  const int lane = t & 63;
  const int wv = t >> 6;
  const int ar = t >> 1;         // A staging: row 0..127
  const int ae = t & 1;          // A staging: 16-half chunk
  const int frow = lane & 15;
  const int fo = lane >> 4;      // fragment k-octet

  const int mbase = (TN == 2) ? (wv >> 1) * 64 : wv * 32;
  const int nbase = (TN == 2) ? (wv & 1) * 64 : 0;

  f32x4 acc[MF][4];
#pragma unroll
  for (int i = 0; i < MF; i++)
#pragma unroll
    for (int j = 0; j < 4; j++) acc[i][j] = (f32x4){0.f, 0.f, 0.f, 0.f};

  int offA[MF], offB[4];
#pragma unroll
  for (int fm = 0; fm < MF; fm++) {
    int r = mbase + fm * 16 + frow;
    offA[fm] = r * 32 + (((fo + (r >> 1)) & 3) * 8);
  }
#pragma unroll
  for (int fn = 0; fn < 4; fn++) {
    int r = nbase + fn * 16 + frow;
    offB[fn] = r * 32 + (((fo + (r >> 1)) & 3) * 8);
  }
  const int p0 = ((2 * ae + 0) + (ar >> 1)) & 3;
  const int p1 = ((2 * ae + 1) + (ar >> 1)) & 3;
  const int br2 = t >> 1, be2 = t & 1;              // TN==2 B staging
  const int br1 = t >> 2, bo1 = t & 3;              // TN==1 B staging
  const int pb1 = (bo1 + (br1 >> 1)) & 3;

  for (int kt = 0; kt < NE; kt += 32) {
    const size_t gofs = (size_t)(m0 + ar) * NE + kt + ae * 16;
    f16x8 av0, av1;
    if (am == 0) {
      const half_t* ap = (const half_t*)A + gofs;
      av0 = *(const f16x8*)ap;
      av1 = *(const f16x8*)(ap + 8);
    } else if (am == 2) {
      const float* ap = (const float*)A + gofs;
      float4 f0 = *(const float4*)ap;
      float4 f1 = *(const float4*)(ap + 4);
      float4 f2 = *(const float4*)(ap + 8);
      float4 f3 = *(const float4*)(ap + 12);
      av0[0] = (half_t)f0.x; av0[1] = (half_t)f0.y; av0[2] = (half_t)f0.z; av0[3] = (half_t)f0.w;
      av0[4] = (half_t)f1.x; av0[5] = (half_t)f1.y; av0[6] = (half_t)f1.z; av0[7] = (half_t)f1.w;
      av1[0] = (half_t)f2.x; av1[1] = (half_t)f2.y; av1[2] = (half_t)f2.z; av1[3] = (half_t)f2.w;
      av1[4] = (half_t)f3.x; av1[5] = (half_t)f3.y; av1[6] = (half_t)f3.z; av1[7] = (half_t)f3.w;
    } else {  // am == 3: silu(a)*a2
      const half_t* ap = (const half_t*)A + gofs;
      const half_t* bp = (const half_t*)A2 + gofs;
      f16x8 a0 = *(const f16x8*)ap;
      f16x8 a1 = *(const f16x8*)(ap + 8);
      f16x8 b0 = *(const f16x8*)bp;
      f16x8 b1 = *(const f16x8*)(bp + 8);
#pragma unroll
      for (int e = 0; e < 8; e++) {
        av0[e] = (half_t)(silu_f((float)a0[e]) * (float)b0[e]);
        av1[e] = (half_t)(silu_f((float)a1[e]) * (float)b1[e]);
      }
    }
    *(f16x8*)&As[ar * 32 + p0 * 8] = av0;
    *(f16x8*)&As[ar * 32 + p1 * 8] = av1;
    if (TN == 2) {
      const half_t* wp = W + (size_t)(n0 + br2) * NE + kt + be2 * 16;
      f16x8 bv0 = *(const f16x8*)wp;
      f16x8 bv1 = *(const f16x8*)(wp + 8);
      *(f16x8*)&Bs[br2 * 32 + p0 * 8] = bv0;
      *(f16x8*)&Bs[br2 * 32 + p1 * 8] = bv1;
    } else {
      const half_t* wp = W + (size_t)(n0 + br1) * NE + kt + bo1 * 8;
      f16x8 bv = *(const f16x8*)wp;
      *(f16x8*)&Bs[br1 * 32 + pb1 * 8] = bv;
    }
    __syncthreads();
    f16x8 af[MF], bf[4];
#pragma unroll
    for (int fm = 0; fm < MF; fm++) af[fm] = *(const f16x8*)&As[offA[fm]];
#pragma unroll
    for (int fn = 0; fn < 4; fn++) bf[fn] = *(const f16x8*)&Bs[offB[fn]];
#pragma unroll
    for (int fm = 0; fm < MF; fm++)
#pragma unroll
      for (int fn = 0; fn < 4; fn++)
        acc[fm][fn] = __builtin_amdgcn_mfma_f32_16x16x32_f16(af[fm], bf[fn], acc[fm][fn], 0, 0, 0);
    __syncthreads();
  }
#pragma unroll
  for (int fm = 0; fm < MF; fm++) {
    int rb = m0 + mbase + fm * 16 + (lane >> 4) * 4;
#pragma unroll
    for (int fn = 0; fn < 4; fn++) {
      int col = n0 + nbase + fn * 16 + frow;
#pragma unroll
      for (int r = 0; r < 4; r++) {
        float val = acc[fm][fn][r] * alpha;
        if (om == 0) ((float*)O)[(size_t)(rb + r) * NE + col] = val;
        else ((half_t*)O)[(size_t)(rb + r) * NE + col] = (half_t)val;
      }
    }
  }
}

// ------- retention pass 1 (MFMA): U_c[d][v] (fp16 out) + carry factor f ------
__global__ __launch_bounds__(256) void ret_pass1_kernel(
    const half_t* __restrict__ kmat, const half_t* __restrict__ vmat,
    const int* __restrict__ seg, const int* __restrict__ ts,
    half_t* __restrict__ U, float* __restrict__ fbuf) {
  __shared__ half_t KT[64 * 72];  // w-scaled K^T: [d][j]
  __shared__ half_t VT[64 * 72];  // V^T: [v][j]
  const int c = blockIdx.x, bh = blockIdx.y;
  const int b = bh >> 3, h = bh & 7;
  const float l2k = h_log2kap(h);
  const int t = threadIdx.x;
  const int r = t & 63, qd = t >> 6;
  const int e = c * CSZ + CSZ - 1;
  const int seg_e = seg[b * NS + e];
  const float ts_e = (float)ts[b * NS + e];
  {
    int gj = b * NS + c * CSZ + r;
    float w = (seg[gj] == seg_e) ? exp2f((ts_e - (float)ts[gj]) * l2k) : 0.0f;
    size_t gbase = (size_t)gj * NE + h * ND + qd * 16;
    f16x8 k0 = *(const f16x8*)&kmat[gbase];
    f16x8 k1 = *(const f16x8*)&kmat[gbase + 8];
    f16x8 v0 = *(const f16x8*)&vmat[gbase];
    f16x8 v1 = *(const f16x8*)&vmat[gbase + 8];
#pragma unroll
    for (int s = 0; s < 8; s++) {
      KT[(qd * 16 + s) * 72 + r] = (half_t)(w * (float)k0[s]);
      KT[(qd * 16 + 8 + s) * 72 + r] = (half_t)(w * (float)k1[s]);
      VT[(qd * 16 + s) * 72 + r] = v0[s];
      VT[(qd * 16 + 8 + s) * 72 + r] = v1[s];
    }
  }
  __syncthreads();
  const int lane = t & 63, wv = t >> 6;
  const int fr = lane & 15, fo8 = (lane >> 4) * 8;
  f32x4 acc[4];
#pragma unroll
  for (int j = 0; j < 4; j++) acc[j] = (f32x4){0.f, 0.f, 0.f, 0.f};
#pragma unroll
  for (int ks = 0; ks < 2; ks++) {
    f16x8 af = *(const f16x8*)&KT[(wv * 16 + fr) * 72 + ks * 32 + fo8];
#pragma unroll
    for (int nt = 0; nt < 4; nt++) {
      f16x8 bf = *(const f16x8*)&VT[(nt * 16 + fr) * 72 + ks * 32 + fo8];
      acc[nt] = __builtin_amdgcn_mfma_f32_16x16x32_f16(af, bf, acc[nt], 0, 0, 0);
    }
  }
  half_t* Uo = U + ((size_t)bh * NC + c) * (ND * ND);
  const int drow = wv * 16 + (lane >> 4) * 4;
#pragma unroll
  for (int nt = 0; nt < 4; nt++)
#pragma unroll
    for (int rg = 0; rg < 4; rg++)
      Uo[(drow + rg) * ND + nt * 16 + fr] = (half_t)acc[nt][rg];
  if (t == 0) {
    int ps = 0;
    float pt = -1.0f;
    if (c > 0) {
      ps = seg[b * NS + c * CSZ - 1];
      pt = (float)ts[b * NS + c * CSZ - 1];
    }
    fbuf[bh * NC + c] = (seg_e == ps) ? exp2f((ts_e - pt) * l2k) : 0.0f;
  }
}

// -- retention pass 2+3 fused: per-block P_c scan from fp16 U, then chunk work.
// Block c==NC computes h_new only. P_c = sum_{c'<c} (prod f) U_c' + (prod f) h0.
__global__ __launch_bounds__(256) void ret_pass23_kernel(
    const half_t* __restrict__ qmat, const half_t* __restrict__ kmat,
    const half_t* __restrict__ vmat, const half_t* __restrict__ U,
    const float* __restrict__ fbuf, const float* __restrict__ hin,
    float* __restrict__ hout, const half_t* __restrict__ gmat,
    const int* __restrict__ seg, const int* __restrict__ ts,
    const float* __restrict__ gns, const float* __restrict__ gnb,
    half_t* __restrict__ y16) {
  __shared__ half_t Qs[64 * 72];  // Q natural [i][d]
  __shared__ half_t KS[64 * 72];  // K natural [j][d]; later Sc [i][j]
  __shared__ half_t VT[64 * 72];  // V^T [v][j]
  __shared__ half_t PT[64 * 72];  // P^T [v][d]
  __shared__ int segs[64];
  __shared__ int tss[64];
  __shared__ float gnsv[64];
  __shared__ float gnbv[64];
  const int c = blockIdx.x, bh = blockIdx.y;
  const int b = bh >> 3, h = bh & 7;
  const float l2k = h_log2kap(h);
  const int t = threadIdx.x;
  const int r = t & 63, qd = t >> 6;
  // ---- P_c scan (in fp32 registers); rows of P: d=r, cols v=qd*16..+15 ----
  float pv[16];
  {
    float coef = 1.0f;
#pragma unroll
    for (int u = 0; u < 16; u++) pv[u] = 0.f;
    for (int cp = c - 1; cp >= 0; --cp) {
      const half_t* up = U + ((size_t)bh * NC + cp) * 4096 + r * 64 + qd * 16;
      f16x8 u0 = *(const f16x8*)up;
      f16x8 u1 = *(const f16x8*)(up + 8);
#pragma unroll
      for (int s = 0; s < 8; s++) {
        pv[s] += coef * (float)u0[s];
        pv[8 + s] += coef * (float)u1[s];
      }
      coef *= fbuf[bh * NC + cp];
    }
    const float* h0 = hin + (size_t)bh * 4096 + r * 64 + qd * 16;
    float hv[16];
    *(float4*)&hv[0] = *(const float4*)h0;
    *(float4*)&hv[4] = *(const float4*)(h0 + 4);
    *(float4*)&hv[8] = *(const float4*)(h0 + 8);
    *(float4*)&hv[12] = *(const float4*)(h0 + 12);
#pragma unroll
    for (int u = 0; u < 16; u++) pv[u] += coef * hv[u];
  }
  if (c == NC) {  // h_new block
    float* ho = hout + (size_t)bh * 4096 + r * 64 + qd * 16;
    *(float4*)ho = *(float4*)&pv[0];
    *(float4*)(ho + 4) = *(float4*)&pv[4];
    *(float4*)(ho + 8) = *(float4*)&pv[8];
    *(float4*)(ho + 12) = *(float4*)&pv[12];
    return;
  }
  // ---- stage Q, K, V, P^T ----
  {
    size_t gbase = (size_t)(b * NS + c * CSZ + r) * NE + h * ND + qd * 16;
    f16x8 q0 = *(const f16x8*)&qmat[gbase];
    f16x8 q1 = *(const f16x8*)&qmat[gbase + 8];
    *(f16x8*)&Qs[r * 72 + qd * 16] = q0;
    *(f16x8*)&Qs[r * 72 + qd * 16 + 8] = q1;
    f16x8 k0 = *(const f16x8*)&kmat[gbase];
    f16x8 k1 = *(const f16x8*)&kmat[gbase + 8];
    *(f16x8*)&KS[r * 72 + qd * 16] = k0;
    *(f16x8*)&KS[r * 72 + qd * 16 + 8] = k1;
    f16x8 v0 = *(const f16x8*)&vmat[gbase];
    f16x8 v1 = *(const f16x8*)&vmat[gbase + 8];
#pragma unroll
    for (int s = 0; s < 8; s++) {
      VT[(qd * 16 + s) * 72 + r] = v0[s];
      VT[(qd * 16 + 8 + s) * 72 + r] = v1[s];
      PT[(qd * 16 + s) * 72 + r] = (half_t)pv[s];
      PT[(qd * 16 + 8 + s) * 72 + r] = (half_t)pv[8 + s];
    }
    if (t < 64) {
      segs[t] = seg[b * NS + c * CSZ + t];
      tss[t] = ts[b * NS + c * CSZ + t];
    } else if (t < 128) {
      gnsv[t - 64] = gns[h * ND + t - 64];
      gnbv[t - 64] = gnb[h * ND + t - 64];
    }
  }
  __syncthreads();
  const int lane = t & 63, wv = t >> 6;
  const int fr = lane & 15, fo8 = (lane >> 4) * 8;
  // ---- QK^T ----
  f32x4 aq[4];
#pragma unroll
  for (int j = 0; j < 4; j++) aq[j] = (f32x4){0.f, 0.f, 0.f, 0.f};
#pragma unroll
  for (int ks = 0; ks < 2; ks++) {
    f16x8 af = *(const f16x8*)&Qs[(wv * 16 + fr) * 72 + ks * 32 + fo8];
#pragma unroll
    for (int nt = 0; nt < 4; nt++) {
      f16x8 bf = *(const f16x8*)&KS[(nt * 16 + fr) * 72 + ks * 32 + fo8];
      aq[nt] = __builtin_amdgcn_mfma_f32_16x16x32_f16(af, bf, aq[nt], 0, 0, 0);
    }
  }
  __syncthreads();  // all K reads done -> KS becomes Sc
  // ---- decay/causal mask, write Sc[i][j] fp16 into KS ----
  const int qrow = wv * 16 + (lane >> 4) * 4;
#pragma unroll
  for (int nt = 0; nt < 4; nt++) {
    int j = nt * 16 + fr;
    int sj = segs[j];
    float tsj = (float)tss[j];
#pragma unroll
    for (int rg = 0; rg < 4; rg++) {
      int i = qrow + rg;
      float w = 0.0f;
      if (j <= i && sj == segs[i]) w = exp2f(((float)tss[i] - tsj) * l2k);
      KS[i * 72 + j] = (half_t)(aq[nt][rg] * w);
    }
  }
  __syncthreads();
  // ---- cross-decay factor g_i for this lane's A-row (i = wv*16 + fr) ----
  float gi;
  {
    int ps = 0;
    float pt = -1.0f;
    if (c > 0) {
      ps = seg[b * NS + c * CSZ - 1];
      pt = (float)ts[b * NS + c * CSZ - 1];
    }
    int i = wv * 16 + fr;
    gi = (segs[i] == ps) ? exp2f(((float)tss[i] - pt) * l2k) : 0.0f;
  }
  // ---- acc = Sc @ V + (g*Q) @ P ----
  f32x4 acc[4];
#pragma unroll
  for (int j = 0; j < 4; j++) acc[j] = (f32x4){0.f, 0.f, 0.f, 0.f};
#pragma unroll
  for (int ks = 0; ks < 2; ks++) {
    f16x8 saf = *(const f16x8*)&KS[(wv * 16 + fr) * 72 + ks * 32 + fo8];
    f16x8 qaf = *(const f16x8*)&Qs[(wv * 16 + fr) * 72 + ks * 32 + fo8];
    f16x8 gqf;
#pragma unroll
    for (int e = 0; e < 8; e++) gqf[e] = (half_t)(gi * (float)qaf[e]);
#pragma unroll
    for (int nt = 0; nt < 4; nt++) {
      f16x8 vbf = *(const f16x8*)&VT[(nt * 16 + fr) * 72 + ks * 32 + fo8];
      acc[nt] = __builtin_amdgcn_mfma_f32_16x16x32_f16(saf, vbf, acc[nt], 0, 0, 0);
      f16x8 pbf = *(const f16x8*)&PT[(nt * 16 + fr) * 72 + ks * 32 + fo8];
      acc[nt] = __builtin_amdgcn_mfma_f32_16x16x32_f16(gqf, pbf, acc[nt], 0, 0, 0);
    }
  }
  // ---- groupnorm over v (64) per row i, then silu(g)-gate, fp16 out ----
#pragma unroll
  for (int rg = 0; rg < 4; rg++) {
    float s1 = acc[0][rg] + acc[1][rg] + acc[2][rg] + acc[3][rg];
    float s2 = acc[0][rg] * acc[0][rg] + acc[1][rg] * acc[1][rg] +
               acc[2][rg] * acc[2][rg] + acc[3][rg] * acc[3][rg];
    s1 += __shfl_xor(s1, 1); s2 += __shfl_xor(s2, 1);
    s1 += __shfl_xor(s1, 2); s2 += __shfl_xor(s2, 2);
    s1 += __shfl_xor(s1, 4); s2 += __shfl_xor(s2, 4);
    s1 += __shfl_xor(s1, 8); s2 += __shfl_xor(s2, 8);
    float mu = s1 * (1.0f / 64.0f);
    float var = s2 * (1.0f / 64.0f) - mu * mu;
    float rs = rsqrtf(var + FEPS);
    int i = qrow + rg;
    size_t ybase = (size_t)(b * NS + c * CSZ + i) * NE + h * ND;
#pragma unroll
    for (int nt = 0; nt < 4; nt++) {
      int col = nt * 16 + fr;
      float gg = (float)gmat[ybase + col];
      float val = (acc[nt][rg] - mu) * rs * gnsv[col] + gnbv[col];
      y16[ybase + col] = (half_t)(silu_f(gg) * val);
    }
  }
}

// -- residual RMS norm; OMODE 0: fp32 out, 1: fp16 out, 2: both. a is fp16. ---
template <int OMODE>
__global__ __launch_bounds__(256) void rms_kernel(const half_t* __restrict__ a,
                                                  const float* __restrict__ res,
                                                  const float* __restrict__ scale,
                                                  float* __restrict__ outf,
                                                  half_t* __restrict__ outh) {
  int row = blockIdx.x * 4 + (threadIdx.x >> 6);
  int lane = threadIdx.x & 63;
  int base = row * NE + lane * 8;
  f16x8 ah = *(const f16x8*)&a[base];
  float x[8], r[8];
  *(float4*)&r[0] = *(const float4*)&res[base];
  *(float4*)&r[4] = *(const float4*)&res[base + 4];
  float ss = 0.f;
#pragma unroll
  for (int u = 0; u < 8; u++) {
    x[u] = (float)ah[u] + r[u];
    ss += x[u] * x[u];
  }
#pragma unroll
  for (int off = 1; off < 64; off <<= 1) ss += __shfl_xor(ss, off);
  float rsf = rsqrtf(ss * (1.0f / 512.0f) + FEPS);
  float s[8];
  *(float4*)&s[0] = *(const float4*)&scale[lane * 8];
  *(float4*)&s[4] = *(const float4*)&scale[lane * 8 + 4];
  float o[8];
#pragma unroll
  for (int u = 0; u < 8; u++) o[u] = x[u] * rsf * s[u];
  if (OMODE == 0 || OMODE == 2) {
    *(float4*)&outf[base] = *(float4*)&o[0];
    *(float4*)&outf[base + 4] = *(float4*)&o[4];
  }
  if (OMODE == 1 || OMODE == 2) {
    f16x8 h;
#pragma unroll
    for (int u = 0; u < 8; u++) h[u] = (half_t)o[u];
    *(f16x8*)&outh[base] = h;
  }
}

extern "C" void kernel_launch(void* const* d_in, const int* in_sizes, int n_in,
                              void* d_out, int out_size, void* d_ws, size_t ws_size,
                              hipStream_t stream) {
  (void)in_sizes; (void)n_in; (void)out_size; (void)ws_size;
  const float* x = (const float*)d_in[0];
  const float* obs = (const float*)d_in[1];
  const float* hs1 = (const float*)d_in[2];
  const float* hs2 = (const float*)d_in[3];
  const int* dones = (const int*)d_in[4];
  const int* tsid = (const int*)d_in[5];
  const float* ln1 = (const float*)d_in[6];
  const float* ln2 = (const float*)d_in[7];
  const float* ln3 = (const float*)d_in[8];
  const float* r1_gs = (const float*)d_in[14];
  const float* r1_gb = (const float*)d_in[15];
  const float* r2_gs = (const float*)d_in[21];
  const float* r2_gb = (const float*)d_in[22];

  const size_t NBUF = (size_t)NB * NS * NE;  // 2,097,152 elements
  char* ws = (char*)d_ws;
  int* segb = (int*)ws;                              // 16 KB
  float* fb = (float*)(ws + 16384);                  // 2 KB
  half_t* W16 = (half_t*)(ws + 18432);               // 13 x 512 KB
  char* p = ws + 18432 + (size_t)13 * NE * NE * sizeof(half_t);
  float* F1 = (float*)p;                 // y (fp32 residual for final rms)
  half_t* Uh = (half_t*)(F1 + NBUF);     // U (fp16), NB*NH*NC*ND*ND = NBUF halfs
  half_t* Hq = Uh + NBUF;
  half_t* Hk = Hq + NBUF;
  half_t* Hv = Hk + NBUF;
  half_t* Hg = Hv + NBUF;
  half_t* H1 = Hg + NBUF;                // pass3 output (gated, fp16)
  half_t* H2 = H1 + NBUF;                // rms fp16 output
  half_t* H3 = H2 + NBUF;                // wo/ffn GEMM fp16 outputs

  float* out = (float*)d_out;
  float* hs1o = out + NBUF;
  float* hs2o = hs1o + (size_t)NB * NH * ND * ND;

  // converted-weight slots: 0..4 = r1 wq,wk,wv,wg,wo; 5..9 = r2 wq,wk,wv,wg,wo;
  // 10..12 = ffn wg,wl,wo
  WCArgs wc;
  wc.src[0] = (const float*)d_in[9];   wc.src[1] = (const float*)d_in[10];
  wc.src[2] = (const float*)d_in[11];  wc.src[3] = (const float*)d_in[12];
  wc.src[4] = (const float*)d_in[13];  wc.src[5] = (const float*)d_in[16];
  wc.src[6] = (const float*)d_in[17];  wc.src[7] = (const float*)d_in[18];
  wc.src[8] = (const float*)d_in[19];  wc.src[9] = (const float*)d_in[20];
  wc.src[10] = (const float*)d_in[24]; wc.src[11] = (const float*)d_in[23];
  wc.src[12] = (const float*)d_in[25];
  wc.dst = W16;
  wc.dones = dones;
  wc.seg = segb;
  const half_t* WS[13];
  for (int i = 0; i < 13; i++) WS[i] = W16 + (size_t)i * NE * NE;

  dim3 gR(16, 32), gR23(17, 32);

  prep_kernel<<<dim3(64, 14), 256, 0, stream>>>(wc);

  // ---- retention layer 1: q,k,v,g = x @ {wq,wk,wv,wg} (cvt fused) ----
  {
    GArgs a = {x, x, x, x, nullptr, nullptr, nullptr, nullptr,
               WS[0], WS[1], WS[2], WS[3], Hq, Hk, Hv, Hg,
               1.0f, 0.125f, 1.0f, 1.0f, 2, 2, 2, 2, 1, 1, 1, 1};
    mfma_gemm_kernel<2><<<dim3(16, 32), 256, 0, stream>>>(a);
  }
  ret_pass1_kernel<<<gR, 256, 0, stream>>>(Hk, Hv, segb, tsid, Uh, fb);
  ret_pass23_kernel<<<gR23, 256, 0, stream>>>(Hq, Hk, Hv, Uh, fb, hs1, hs1o,
                                              Hg, segb, tsid, r1_gs, r1_gb, H1);
  {  // o1 = H1 @ wo -> H3 (fp16)
    GArgs a = {H1, H1, H1, H1, nullptr, nullptr, nullptr, nullptr,
               WS[4], WS[4], WS[4], WS[4], H3, H3, H3, H3,
               1.0f, 1.0f, 1.0f, 1.0f, 0, 0, 0, 0, 1, 1, 1, 1};
    mfma_gemm_kernel<1><<<dim3(8, 32), 256, 0, stream>>>(a);
  }
  rms_kernel<1><<<1024, 256, 0, stream>>>(H3, x, ln1, nullptr, H2);  // x2 -> H2

  // ---- retention layer 2: q2,g2 = obs@{wq,wg} (cvt); k2,v2 = x2@{wk,wv} ----
  {
    GArgs a = {obs, obs, H2, H2, nullptr, nullptr, nullptr, nullptr,
               WS[5], WS[8], WS[6], WS[7], Hq, Hg, Hk, Hv,
               1.0f, 1.0f, 0.125f, 1.0f, 2, 2, 0, 0, 1, 1, 1, 1};
    mfma_gemm_kernel<2><<<dim3(16, 32), 256, 0, stream>>>(a);
  }
  ret_pass1_kernel<<<gR, 256, 0, stream>>>(Hk, Hv, segb, tsid, Uh, fb);
  ret_pass23_kernel<<<gR23, 256, 0, stream>>>(Hq, Hk, Hv, Uh, fb, hs2, hs2o,
                                              Hg, segb, tsid, r2_gs, r2_gb, H1);
  {  // o2 = H1 @ wo -> H3
    GArgs a = {H1, H1, H1, H1, nullptr, nullptr, nullptr, nullptr,
               WS[9], WS[9], WS[9], WS[9], H3, H3, H3, H3,
               1.0f, 1.0f, 1.0f, 1.0f, 0, 0, 0, 0, 1, 1, 1, 1};
    mfma_gemm_kernel<1><<<dim3(8, 32), 256, 0, stream>>>(a);
  }
  rms_kernel<2><<<1024, 256, 0, stream>>>(H3, obs, ln2, F1, H2);  // y -> F1 + H2

  // ---- FFN: wg,wl from H2 -> Hq,Hk (fp16); fused silu in wo staging ----
  {
    GArgs a = {H2, H2, H2, H2, nullptr, nullptr, nullptr, nullptr,
               WS[10], WS[11], WS[10], WS[11], Hq, Hk, Hq, Hk,
               1.0f, 1.0f, 1.0f, 1.0f, 0, 0, 0, 0, 1, 1, 1, 1};
    mfma_gemm_kernel<2><<<dim3(8, 32), 256, 0, stream>>>(a);
  }
  {  // ffn = (silu(Hq) * Hk) @ wo -> H3
    GArgs a = {Hq, Hq, Hq, Hq, Hk, Hk, Hk, Hk,
               WS[12], WS[12], WS[12], WS[12], H3, H3, H3, H3,
               1.0f, 1.0f, 1.0f, 1.0f, 3, 3, 3, 3, 1, 1, 1, 1};
    mfma_gemm_kernel<1><<<dim3(8, 32), 256, 0, stream>>>(a);
  }
  rms_kernel<0><<<1024, 256, 0, stream>>>(H3, F1, ln3, out, nullptr);
}

// Round 9
// 276.311 us; speedup vs baseline: 1.0997x; 1.0997x over previous
//
#include <hip/hip_runtime.h>

#define NB 4
#define NS 1024
#define NE 512
#define NH 8
#define ND 64
#define NC 16      // chunks per sequence
#define CSZ 64     // chunk size

static constexpr float FEPS = 1e-6f;

typedef _Float16 half_t;
typedef __attribute__((ext_vector_type(8))) _Float16 f16x8;
typedef __attribute__((ext_vector_type(4))) float f32x4;

__device__ __forceinline__ float h_log2kap(int h) {
  float kap = (1.0f - exp2f(-5.0f - (float)h)) * 0.8f;
  return log2f(kap);
}
__device__ __forceinline__ float silu_f(float x) {
  return x / (1.0f + __expf(-x));
}
// async global->LDS, 16 bytes per lane; LDS base must be wave-uniform
__device__ __forceinline__ void gload_lds16(const half_t* g, half_t* l) {
  __builtin_amdgcn_global_load_lds(
      (const __attribute__((address_space(1))) unsigned int*)g,
      (__attribute__((address_space(3))) unsigned int*)l, 16, 0, 0);
}

// -- prep: weight convert+transpose (13 mats) + segment scan + x/obs -> fp16 --
struct WCArgs {
  const float* src[13];
  half_t* dst;
  const int* dones;
  int* seg;
  const float* x;
  const float* obs;
  half_t* hx;
  half_t* hobs;
};
__global__ __launch_bounds__(256) void prep_kernel(WCArgs a) {
  __shared__ half_t T[64][72];  // [k][n] tile, padded
  __shared__ int s[NS];
  const int t = threadIdx.x;
  if (blockIdx.y < 13) {
    if (blockIdx.x >= 64) return;
    const int w = blockIdx.y;
    const int kt = (blockIdx.x & 7) * 64;
    const int nt = (blockIdx.x >> 3) * 64;
    const float* src = a.src[w] + (size_t)kt * NE + nt;
    const int c = t & 63;
    for (int r = t >> 6; r < 64; r += 4) T[r][c] = (half_t)src[(size_t)r * NE + c];
    __syncthreads();
    const int n = t >> 2, kq = (t & 3) * 16;
    half_t* dst = a.dst + (size_t)w * NE * NE + (size_t)(nt + n) * NE + kt + kq;
    f16x8 o0, o1;
#pragma unroll
    for (int j = 0; j < 8; j++) {
      o0[j] = T[kq + j][n];
      o1[j] = T[kq + 8 + j][n];
    }
    *(f16x8*)dst = o0;
    *(f16x8*)(dst + 8) = o1;
  } else if (blockIdx.y == 13) {
    if (blockIdx.x >= NB) return;
    const int b = blockIdx.x;
    for (int i = t; i < NS; i += 256) s[i] = (a.dones[b * NS + i] != 0) ? 1 : 0;
    __syncthreads();
    for (int off = 1; off < NS; off <<= 1) {
      int tv[4];
#pragma unroll
      for (int u = 0; u < 4; u++) {
        int i = t + 256 * u;
        tv[u] = s[i] + ((i >= off) ? s[i - off] : 0);
      }
      __syncthreads();
#pragma unroll
      for (int u = 0; u < 4; u++) s[t + 256 * u] = tv[u];
      __syncthreads();
    }
    for (int i = t; i < NS; i += 256) a.seg[b * NS + i] = s[i];
  } else {
    // convert x and obs to fp16
    size_t i = ((size_t)blockIdx.x * 256 + t) * 8;
    float4 v0 = *(const float4*)&a.x[i];
    float4 v1 = *(const float4*)&a.x[i + 4];
    f16x8 h;
    h[0] = (half_t)v0.x; h[1] = (half_t)v0.y; h[2] = (half_t)v0.z; h[3] = (half_t)v0.w;
    h[4] = (half_t)v1.x; h[5] = (half_t)v1.y; h[6] = (half_t)v1.z; h[7] = (half_t)v1.w;
    *(f16x8*)&a.hx[i] = h;
    float4 w0 = *(const float4*)&a.obs[i];
    float4 w1 = *(const float4*)&a.obs[i + 4];
    f16x8 g;
    g[0] = (half_t)w0.x; g[1] = (half_t)w0.y; g[2] = (half_t)w0.z; g[3] = (half_t)w0.w;
    g[4] = (half_t)w1.x; g[5] = (half_t)w1.y; g[6] = (half_t)w1.z; g[7] = (half_t)w1.w;
    *(f16x8*)&a.hobs[i] = g;
  }
}

// ---- fp16 MFMA GEMM (m97-style): O[w] = f(A[w]) @ Wt[w]^T * alpha[w], fp16 out
// Tile 128x128, BK=64 halfs, 4 waves (64x64 quadrant each, acc 4x4).
// A/B staged via global_load_lds width=16; LDS rows 128B, octet swizzle
// p = o ^ (row&7) -> bank load balanced at the structural floor.
// amode: 0 = A fp16 (async path); 3 = silu(A)*A2 elementwise (VGPR staging).
struct GArgs {
  const half_t *A0, *A1, *A2i, *A3;
  const half_t *B0, *B1, *B2, *B3;   // second operand for amode 3
  const half_t *W0, *W1, *W2, *W3;
  half_t *O0, *O1, *O2, *O3;
  float a0, a1, a2, a3;
  int am0, am1, am2, am3;
};

__global__ __launch_bounds__(256) void mfma_gemm_kernel(GArgs g) {
  __shared__ half_t As[128 * 64];
  __shared__ half_t Bs[128 * 64];
  const int t = threadIdx.x;
  const int bn = blockIdx.x;
  const int wsel = bn >> 2;
  const int n0 = (bn & 3) * 128;
  const int m0 = blockIdx.y * 128;
  const half_t* A = wsel == 0 ? g.A0 : wsel == 1 ? g.A1 : wsel == 2 ? g.A2i : g.A3;
  const half_t* A2 = wsel == 0 ? g.B0 : wsel == 1 ? g.B1 : wsel == 2 ? g.B2 : g.B3;
  const half_t* W = wsel == 0 ? g.W0 : wsel == 1 ? g.W1 : wsel == 2 ? g.W2 : g.W3;
  half_t* O = wsel == 0 ? g.O0 : wsel == 1 ? g.O1 : wsel == 2 ? g.O2 : g.O3;
  const float alpha = wsel == 0 ? g.a0 : wsel == 1 ? g.a1 : wsel == 2 ? g.a2 : g.a3;
  const int am = wsel == 0 ? g.am0 : wsel == 1 ? g.am1 : wsel == 2 ? g.am2 : g.am3;
  const int lane = t & 63;
  const int wv = t >> 6;
  const int frow = lane & 15;
  const int fo = lane >> 4;
  const int mbase = (wv & 1) * 64;
  const int nbase = (wv >> 1) * 64;

  f32x4 acc[4][4];
#pragma unroll
  for (int i = 0; i < 4; i++)
#pragma unroll
    for (int j = 0; j < 4; j++) acc[i][j] = (f32x4){0.f, 0.f, 0.f, 0.f};

  // fragment LDS offsets (halfs): row*64 + (oct ^ (row&7))*8, oct = ks*4+fo
  int offA[2][4], offB[2][4];
#pragma unroll
  for (int ks = 0; ks < 2; ks++)
#pragma unroll
    for (int f = 0; f < 4; f++) {
      int ra = mbase + f * 16 + frow;
      offA[ks][f] = ra * 64 + (((ks * 4 + fo) ^ (ra & 7)) * 8);
      int rb = nbase + f * 16 + frow;
      offB[ks][f] = rb * 64 + (((ks * 4 + fo) ^ (rb & 7)) * 8);
    }
  // staging: flat f = rnd*256 + t; row = f>>3, phys octet p = f&7,
  // source octet o = p ^ (row&7); dest halfs offset = f*8 (lane*16B within wave)
  int srow[4], soct[4];
#pragma unroll
  for (int r = 0; r < 4; r++) {
    int f = r * 256 + t;
    srow[r] = f >> 3;
    soct[r] = (f & 7) ^ (srow[r] & 7);
  }
  const int ldsb = (t & 192) * 8;  // wave-uniform base (halfs) within a round

  for (int kt = 0; kt < NE; kt += 64) {
    if (am == 0) {
#pragma unroll
      for (int r = 0; r < 4; r++)
        gload_lds16(A + (size_t)(m0 + srow[r]) * NE + kt + soct[r] * 8,
                    &As[r * 2048 + ldsb]);
    } else {  // am == 3: silu(A)*A2
#pragma unroll
      for (int r = 0; r < 4; r++) {
        size_t gofs = (size_t)(m0 + srow[r]) * NE + kt + soct[r] * 8;
        f16x8 av = *(const f16x8*)(A + gofs);
        f16x8 bv = *(const f16x8*)(A2 + gofs);
        f16x8 ov;
#pragma unroll
        for (int e = 0; e < 8; e++)
          ov[e] = (half_t)(silu_f((float)av[e]) * (float)bv[e]);
        *(f16x8*)&As[(r * 256 + t) * 8] = ov;
      }
    }
#pragma unroll
    for (int r = 0; r < 4; r++)
      gload_lds16(W + (size_t)(n0 + srow[r]) * NE + kt + soct[r] * 8,
                  &Bs[r * 2048 + ldsb]);
    __syncthreads();
#pragma unroll
    for (int ks = 0; ks < 2; ks++) {
      f16x8 af[4], bf[4];
#pragma unroll
      for (int f = 0; f < 4; f++) af[f] = *(const f16x8*)&As[offA[ks][f]];
#pragma unroll
      for (int f = 0; f < 4; f++) bf[f] = *(const f16x8*)&Bs[offB[ks][f]];
#pragma unroll
      for (int fm = 0; fm < 4; fm++)
#pragma unroll
        for (int fn = 0; fn < 4; fn++)
          acc[fm][fn] = __builtin_amdgcn_mfma_f32_16x16x32_f16(af[fm], bf[fn], acc[fm][fn], 0, 0, 0);
    }
    __syncthreads();
  }
  // epilogue: C/D layout col=lane&15, row=(lane>>4)*4+reg
#pragma unroll
  for (int fm = 0; fm < 4; fm++) {
    int rb = m0 + mbase + fm * 16 + fo * 4;
#pragma unroll
    for (int fn = 0; fn < 4; fn++) {
      int col = n0 + nbase + fn * 16 + frow;
#pragma unroll
      for (int r = 0; r < 4; r++)
        O[(size_t)(rb + r) * NE + col] = (half_t)(acc[fm][fn][r] * alpha);
    }
  }
}

// ------- retention pass 1 (MFMA): U_c[d][v] (fp16 out) + carry factor f ------
__global__ __launch_bounds__(256) void ret_pass1_kernel(
    const half_t* __restrict__ kmat, const half_t* __restrict__ vmat,
    const int* __restrict__ seg, const int* __restrict__ ts,
    half_t* __restrict__ U, float* __restrict__ fbuf) {
  __shared__ half_t KT[64 * 72];  // w-scaled K^T: [d][j]
  __shared__ half_t VT[64 * 72];  // V^T: [v][j]
  const int c = blockIdx.x, bh = blockIdx.y;
  const int b = bh >> 3, h = bh & 7;
  const float l2k = h_log2kap(h);
  const int t = threadIdx.x;
  const int r = t & 63, qd = t >> 6;
  const int e = c * CSZ + CSZ - 1;
  const int seg_e = seg[b * NS + e];
  const float ts_e = (float)ts[b * NS + e];
  {
    int gj = b * NS + c * CSZ + r;
    float w = (seg[gj] == seg_e) ? exp2f((ts_e - (float)ts[gj]) * l2k) : 0.0f;
    size_t gbase = (size_t)gj * NE + h * ND + qd * 16;
    f16x8 k0 = *(const f16x8*)&kmat[gbase];
    f16x8 k1 = *(const f16x8*)&kmat[gbase + 8];
    f16x8 v0 = *(const f16x8*)&vmat[gbase];
    f16x8 v1 = *(const f16x8*)&vmat[gbase + 8];
#pragma unroll
    for (int s = 0; s < 8; s++) {
      KT[(qd * 16 + s) * 72 + r] = (half_t)(w * (float)k0[s]);
      KT[(qd * 16 + 8 + s) * 72 + r] = (half_t)(w * (float)k1[s]);
      VT[(qd * 16 + s) * 72 + r] = v0[s];
      VT[(qd * 16 + 8 + s) * 72 + r] = v1[s];
    }
  }
  __syncthreads();
  const int lane = t & 63, wv = t >> 6;
  const int fr = lane & 15, fo8 = (lane >> 4) * 8;
  f32x4 acc[4];
#pragma unroll
  for (int j = 0; j < 4; j++) acc[j] = (f32x4){0.f, 0.f, 0.f, 0.f};
#pragma unroll
  for (int ks = 0; ks < 2; ks++) {
    f16x8 af = *(const f16x8*)&KT[(wv * 16 + fr) * 72 + ks * 32 + fo8];
#pragma unroll
    for (int nt = 0; nt < 4; nt++) {
      f16x8 bf = *(const f16x8*)&VT[(nt * 16 + fr) * 72 + ks * 32 + fo8];
      acc[nt] = __builtin_amdgcn_mfma_f32_16x16x32_f16(af, bf, acc[nt], 0, 0, 0);
    }
  }
  half_t* Uo = U + ((size_t)bh * NC + c) * (ND * ND);
  const int drow = wv * 16 + (lane >> 4) * 4;
#pragma unroll
  for (int nt = 0; nt < 4; nt++)
#pragma unroll
    for (int rg = 0; rg < 4; rg++)
      Uo[(drow + rg) * ND + nt * 16 + fr] = (half_t)acc[nt][rg];
  if (t == 0) {
    int ps = 0;
    float pt = -1.0f;
    if (c > 0) {
      ps = seg[b * NS + c * CSZ - 1];
      pt = (float)ts[b * NS + c * CSZ - 1];
    }
    fbuf[bh * NC + c] = (seg_e == ps) ? exp2f((ts_e - pt) * l2k) : 0.0f;
  }
}

// -- retention pass 2+3 fused: per-block P_c scan from fp16 U, then chunk work.
__global__ __launch_bounds__(256) void ret_pass23_kernel(
    const half_t* __restrict__ qmat, const half_t* __restrict__ kmat,
    const half_t* __restrict__ vmat, const half_t* __restrict__ U,
    const float* __restrict__ fbuf, const float* __restrict__ hin,
    float* __restrict__ hout, const half_t* __restrict__ gmat,
    const int* __restrict__ seg, const int* __restrict__ ts,
    const float* __restrict__ gns, const float* __restrict__ gnb,
    half_t* __restrict__ y16) {
  __shared__ half_t Qs[64 * 72];
  __shared__ half_t KS[64 * 72];
  __shared__ half_t VT[64 * 72];
  __shared__ half_t PT[64 * 72];
  __shared__ int segs[64];
  __shared__ int tss[64];
  __shared__ float gnsv[64];
  __shared__ float gnbv[64];
  const int c = blockIdx.x, bh = blockIdx.y;
  const int b = bh >> 3, h = bh & 7;
  const float l2k = h_log2kap(h);
  const int t = threadIdx.x;
  const int r = t & 63, qd = t >> 6;
  float pv[16];
  {
    float coef = 1.0f;
#pragma unroll
    for (int u = 0; u < 16; u++) pv[u] = 0.f;
    for (int cp = c - 1; cp >= 0; --cp) {
      const half_t* up = U + ((size_t)bh * NC + cp) * 4096 + r * 64 + qd * 16;
      f16x8 u0 = *(const f16x8*)up;
      f16x8 u1 = *(const f16x8*)(up + 8);
#pragma unroll
      for (int s = 0; s < 8; s++) {
        pv[s] += coef * (float)u0[s];
        pv[8 + s] += coef * (float)u1[s];
      }
      coef *= fbuf[bh * NC + cp];
    }
    const float* h0 = hin + (size_t)bh * 4096 + r * 64 + qd * 16;
    float hv[16];
    *(float4*)&hv[0] = *(const float4*)h0;
    *(float4*)&hv[4] = *(const float4*)(h0 + 4);
    *(float4*)&hv[8] = *(const float4*)(h0 + 8);
    *(float4*)&hv[12] = *(const float4*)(h0 + 12);
#pragma unroll
    for (int u = 0; u < 16; u++) pv[u] += coef * hv[u];
  }
  if (c == NC) {
    float* ho = hout + (size_t)bh * 4096 + r * 64 + qd * 16;
    *(float4*)ho = *(float4*)&pv[0];
    *(float4*)(ho + 4) = *(float4*)&pv[4];
    *(float4*)(ho + 8) = *(float4*)&pv[8];
    *(float4*)(ho + 12) = *(float4*)&pv[12];
    return;
  }
  {
    size_t gbase = (size_t)(b * NS + c * CSZ + r) * NE + h * ND + qd * 16;
    f16x8 q0 = *(const f16x8*)&qmat[gbase];
    f16x8 q1 = *(const f16x8*)&qmat[gbase + 8];
    *(f16x8*)&Qs[r * 72 + qd * 16] = q0;
    *(f16x8*)&Qs[r * 72 + qd * 16 + 8] = q1;
    f16x8 k0 = *(const f16x8*)&kmat[gbase];
    f16x8 k1 = *(const f16x8*)&kmat[gbase + 8];
    *(f16x8*)&KS[r * 72 + qd * 16] = k0;
    *(f16x8*)&KS[r * 72 + qd * 16 + 8] = k1;
    f16x8 v0 = *(const f16x8*)&vmat[gbase];
    f16x8 v1 = *(const f16x8*)&vmat[gbase + 8];
#pragma unroll
    for (int s = 0; s < 8; s++) {
      VT[(qd * 16 + s) * 72 + r] = v0[s];
      VT[(qd * 16 + 8 + s) * 72 + r] = v1[s];
      PT[(qd * 16 + s) * 72 + r] = (half_t)pv[s];
      PT[(qd * 16 + 8 + s) * 72 + r] = (half_t)pv[8 + s];
    }
    if (t < 64) {
      segs[t] = seg[b * NS + c * CSZ + t];
      tss[t] = ts[b * NS + c * CSZ + t];
    } else if (t < 128) {
      gnsv[t - 64] = gns[h * ND + t - 64];
      gnbv[t - 64] = gnb[h * ND + t - 64];
    }
  }
  __syncthreads();
  const int lane = t & 63, wv = t >> 6;
  const int fr = lane & 15, fo8 = (lane >> 4) * 8;
  f32x4 aq[4];
#pragma unroll
  for (int j = 0; j < 4; j++) aq[j] = (f32x4){0.f, 0.f, 0.f, 0.f};
#pragma unroll
  for (int ks = 0; ks < 2; ks++) {
    f16x8 af = *(const f16x8*)&Qs[(wv * 16 + fr) * 72 + ks * 32 + fo8];
#pragma unroll
    for (int nt = 0; nt < 4; nt++) {
      f16x8 bf = *(const f16x8*)&KS[(nt * 16 + fr) * 72 + ks * 32 + fo8];
      aq[nt] = __builtin_amdgcn_mfma_f32_16x16x32_f16(af, bf, aq[nt], 0, 0, 0);
    }
  }
  __syncthreads();
  const int qrow = wv * 16 + (lane >> 4) * 4;
#pragma unroll
  for (int nt = 0; nt < 4; nt++) {
    int j = nt * 16 + fr;
    int sj = segs[j];
    float tsj = (float)tss[j];
#pragma unroll
    for (int rg = 0; rg < 4; rg++) {
      int i = qrow + rg;
      float w = 0.0f;
      if (j <= i && sj == segs[i]) w = exp2f(((float)tss[i] - tsj) * l2k);
      KS[i * 72 + j] = (half_t)(aq[nt][rg] * w);
    }
  }
  __syncthreads();
  float gi;
  {
    int ps = 0;
    float pt = -1.0f;
    if (c > 0) {
      ps = seg[b * NS + c * CSZ - 1];
      pt = (float)ts[b * NS + c * CSZ - 1];
    }
    int i = wv * 16 + fr;
    gi = (segs[i] == ps) ? exp2f(((float)tss[i] - pt) * l2k) : 0.0f;
  }
  f32x4 acc[4];
#pragma unroll
  for (int j = 0; j < 4; j++) acc[j] = (f32x4){0.f, 0.f, 0.f, 0.f};
#pragma unroll
  for (int ks = 0; ks < 2; ks++) {
    f16x8 saf = *(const f16x8*)&KS[(wv * 16 + fr) * 72 + ks * 32 + fo8];
    f16x8 qaf = *(const f16x8*)&Qs[(wv * 16 + fr) * 72 + ks * 32 + fo8];
    f16x8 gqf;
#pragma unroll
    for (int e = 0; e < 8; e++) gqf[e] = (half_t)(gi * (float)qaf[e]);
#pragma unroll
    for (int nt = 0; nt < 4; nt++) {
      f16x8 vbf = *(const f16x8*)&VT[(nt * 16 + fr) * 72 + ks * 32 + fo8];
      acc[nt] = __builtin_amdgcn_mfma_f32_16x16x32_f16(saf, vbf, acc[nt], 0, 0, 0);
      f16x8 pbf = *(const f16x8*)&PT[(nt * 16 + fr) * 72 + ks * 32 + fo8];
      acc[nt] = __builtin_amdgcn_mfma_f32_16x16x32_f16(gqf, pbf, acc[nt], 0, 0, 0);
    }
  }
#pragma unroll
  for (int rg = 0; rg < 4; rg++) {
    float s1 = acc[0][rg] + acc[1][rg] + acc[2][rg] + acc[3][rg];
    float s2 = acc[0][rg] * acc[0][rg] + acc[1][rg] * acc[1][rg] +
               acc[2][rg] * acc[2][rg] + acc[3][rg] * acc[3][rg];
    s1 += __shfl_xor(s1, 1); s2 += __shfl_xor(s2, 1);
    s1 += __shfl_xor(s1, 2); s2 += __shfl_xor(s2, 2);
    s1 += __shfl_xor(s1, 4); s2 += __shfl_xor(s2, 4);
    s1 += __shfl_xor(s1, 8); s2 += __shfl_xor(s2, 8);
    float mu = s1 * (1.0f / 64.0f);
    float var = s2 * (1.0f / 64.0f) - mu * mu;
    float rs = rsqrtf(var + FEPS);
    int i = qrow + rg;
    size_t ybase = (size_t)(b * NS + c * CSZ + i) * NE + h * ND;
#pragma unroll
    for (int nt = 0; nt < 4; nt++) {
      int col = nt * 16 + fr;
      float gg = (float)gmat[ybase + col];
      float val = (acc[nt][rg] - mu) * rs * gnsv[col] + gnbv[col];
      y16[ybase + col] = (half_t)(silu_f(gg) * val);
    }
  }
}

// -- residual RMS norm; OMODE 0: fp32 out, 1: fp16 out, 2: both. a is fp16. ---
template <int OMODE>
__global__ __launch_bounds__(256) void rms_kernel(const half_t* __restrict__ a,
                                                  const float* __restrict__ res,
                                                  const float* __restrict__ scale,
                                                  float* __restrict__ outf,
                                                  half_t* __restrict__ outh) {
  int row = blockIdx.x * 4 + (threadIdx.x >> 6);
  int lane = threadIdx.x & 63;
  int base = row * NE + lane * 8;
  f16x8 ah = *(const f16x8*)&a[base];
  float x[8], r[8];
  *(float4*)&r[0] = *(const float4*)&res[base];
  *(float4*)&r[4] = *(const float4*)&res[base + 4];
  float ss = 0.f;
#pragma unroll
  for (int u = 0; u < 8; u++) {
    x[u] = (float)ah[u] + r[u];
    ss += x[u] * x[u];
  }
#pragma unroll
  for (int off = 1; off < 64; off <<= 1) ss += __shfl_xor(ss, off);
  float rsf = rsqrtf(ss * (1.0f / 512.0f) + FEPS);
  float s[8];
  *(float4*)&s[0] = *(const float4*)&scale[lane * 8];
  *(float4*)&s[4] = *(const float4*)&scale[lane * 8 + 4];
  float o[8];
#pragma unroll
  for (int u = 0; u < 8; u++) o[u] = x[u] * rsf * s[u];
  if (OMODE == 0 || OMODE == 2) {
    *(float4*)&outf[base] = *(float4*)&o[0];
    *(float4*)&outf[base + 4] = *(float4*)&o[4];
  }
  if (OMODE == 1 || OMODE == 2) {
    f16x8 h;
#pragma unroll
    for (int u = 0; u < 8; u++) h[u] = (half_t)o[u];
    *(f16x8*)&outh[base] = h;
  }
}

extern "C" void kernel_launch(void* const* d_in, const int* in_sizes, int n_in,
                              void* d_out, int out_size, void* d_ws, size_t ws_size,
                              hipStream_t stream) {
  (void)in_sizes; (void)n_in; (void)out_size; (void)ws_size;
  const float* x = (const float*)d_in[0];
  const float* obs = (const float*)d_in[1];
  const float* hs1 = (const float*)d_in[2];
  const float* hs2 = (const float*)d_in[3];
  const int* dones = (const int*)d_in[4];
  const int* tsid = (const int*)d_in[5];
  const float* ln1 = (const float*)d_in[6];
  const float* ln2 = (const float*)d_in[7];
  const float* ln3 = (const float*)d_in[8];
  const float* r1_gs = (const float*)d_in[14];
  const float* r1_gb = (const float*)d_in[15];
  const float* r2_gs = (const float*)d_in[21];
  const float* r2_gb = (const float*)d_in[22];

  const size_t NBUF = (size_t)NB * NS * NE;  // 2,097,152 elements
  char* ws = (char*)d_ws;
  int* segb = (int*)ws;                              // 16 KB
  float* fb = (float*)(ws + 16384);                  // 2 KB
  half_t* W16 = (half_t*)(ws + 18432);               // 13 x 512 KB
  char* p = ws + 18432 + (size_t)13 * NE * NE * sizeof(half_t);
  float* F1 = (float*)p;                 // y (fp32 residual for final rms)
  half_t* Uh = (half_t*)(F1 + NBUF);     // U (fp16)
  half_t* Hq = Uh + NBUF;
  half_t* Hk = Hq + NBUF;
  half_t* Hv = Hk + NBUF;
  half_t* Hg = Hv + NBUF;
  half_t* H1 = Hg + NBUF;                // pass3 output (gated, fp16)
  half_t* H2 = H1 + NBUF;                // rms fp16 output
  half_t* H3 = H2 + NBUF;                // wo/ffn GEMM fp16 outputs
  half_t* Hx = H3 + NBUF;                // x fp16
  half_t* Hobs = Hx + NBUF;              // obs fp16

  float* out = (float*)d_out;
  float* hs1o = out + NBUF;
  float* hs2o = hs1o + (size_t)NB * NH * ND * ND;

  WCArgs wc;
  wc.src[0] = (const float*)d_in[9];   wc.src[1] = (const float*)d_in[10];
  wc.src[2] = (const float*)d_in[11];  wc.src[3] = (const float*)d_in[12];
  wc.src[4] = (const float*)d_in[13];  wc.src[5] = (const float*)d_in[16];
  wc.src[6] = (const float*)d_in[17];  wc.src[7] = (const float*)d_in[18];
  wc.src[8] = (const float*)d_in[19];  wc.src[9] = (const float*)d_in[20];
  wc.src[10] = (const float*)d_in[24]; wc.src[11] = (const float*)d_in[23];
  wc.src[12] = (const float*)d_in[25];
  wc.dst = W16;
  wc.dones = dones;
  wc.seg = segb;
  wc.x = x; wc.obs = obs; wc.hx = Hx; wc.hobs = Hobs;
  const half_t* WS[13];
  for (int i = 0; i < 13; i++) WS[i] = W16 + (size_t)i * NE * NE;

  dim3 gR(16, 32), gR23(17, 32);

  prep_kernel<<<dim3(1024, 15), 256, 0, stream>>>(wc);

  // ---- retention layer 1: q,k,v,g = x16 @ {wq,wk,wv,wg} ----
  {
    GArgs a = {Hx, Hx, Hx, Hx, nullptr, nullptr, nullptr, nullptr,
               WS[0], WS[1], WS[2], WS[3], Hq, Hk, Hv, Hg,
               1.0f, 0.125f, 1.0f, 1.0f, 0, 0, 0, 0};
    mfma_gemm_kernel<<<dim3(16, 32), 256, 0, stream>>>(a);
  }
  ret_pass1_kernel<<<gR, 256, 0, stream>>>(Hk, Hv, segb, tsid, Uh, fb);
  ret_pass23_kernel<<<gR23, 256, 0, stream>>>(Hq, Hk, Hv, Uh, fb, hs1, hs1o,
                                              Hg, segb, tsid, r1_gs, r1_gb, H1);
  {  // o1 = H1 @ wo -> H3 (fp16)
    GArgs a = {H1, H1, H1, H1, nullptr, nullptr, nullptr, nullptr,
               WS[4], WS[4], WS[4], WS[4], H3, H3, H3, H3,
               1.0f, 1.0f, 1.0f, 1.0f, 0, 0, 0, 0};
    mfma_gemm_kernel<<<dim3(4, 32), 256, 0, stream>>>(a);
  }
  rms_kernel<1><<<1024, 256, 0, stream>>>(H3, x, ln1, nullptr, H2);  // x2 -> H2

  // ---- retention layer 2: q2,g2 = obs16@{wq,wg}; k2,v2 = x2@{wk,wv} ----
  {
    GArgs a = {Hobs, Hobs, H2, H2, nullptr, nullptr, nullptr, nullptr,
               WS[5], WS[8], WS[6], WS[7], Hq, Hg, Hk, Hv,
               1.0f, 1.0f, 0.125f, 1.0f, 0, 0, 0, 0};
    mfma_gemm_kernel<<<dim3(16, 32), 256, 0, stream>>>(a);
  }
  ret_pass1_kernel<<<gR, 256, 0, stream>>>(Hk, Hv, segb, tsid, Uh, fb);
  ret_pass23_kernel<<<gR23, 256, 0, stream>>>(Hq, Hk, Hv, Uh, fb, hs2, hs2o,
                                              Hg, segb, tsid, r2_gs, r2_gb, H1);
  {  // o2 = H1 @ wo -> H3
    GArgs a = {H1, H1, H1, H1, nullptr, nullptr, nullptr, nullptr,
               WS[9], WS[9], WS[9], WS[9], H3, H3, H3, H3,
               1.0f, 1.0f, 1.0f, 1.0f, 0, 0, 0, 0};
    mfma_gemm_kernel<<<dim3(4, 32), 256, 0, stream>>>(a);
  }
  rms_kernel<2><<<1024, 256, 0, stream>>>(H3, obs, ln2, F1, H2);  // y -> F1 + H2

  // ---- FFN: wg,wl from H2 -> Hq,Hk (fp16); fused silu in wo staging ----
  {
    GArgs a = {H2, H2, H2, H2, nullptr, nullptr, nullptr, nullptr,
               WS[10], WS[11], WS[10], WS[11], Hq, Hk, Hq, Hk,
               1.0f, 1.0f, 1.0f, 1.0f, 0, 0, 0, 0};
    mfma_gemm_kernel<<<dim3(8, 32), 256, 0, stream>>>(a);
  }
  {  // ffn = (silu(Hq) * Hk) @ wo -> H3
    GArgs a = {Hq, Hq, Hq, Hq, Hk, Hk, Hk, Hk,
               WS[12], WS[12], WS[12], WS[12], H3, H3, H3, H3,
               1.0f, 1.0f, 1.0f, 1.0f, 3, 3, 3, 3};
    mfma_gemm_kernel<<<dim3(4, 32), 256, 0, stream>>>(a);
  }
  rms_kernel<0><<<1024, 256, 0, stream>>>(H3, F1, ln3, out, nullptr);
}

// Round 10
// 258.417 us; speedup vs baseline: 1.1758x; 1.0692x over previous
//
#include <hip/hip_runtime.h>

#define NB 4
#define NS 1024
#define NE 512
#define NH 8
#define ND 64
#define NC 16      // chunks per sequence
#define CSZ 64     // chunk size

static constexpr float FEPS = 1e-6f;

typedef _Float16 half_t;
typedef __attribute__((ext_vector_type(8))) _Float16 f16x8;
typedef __attribute__((ext_vector_type(4))) float f32x4;

__device__ __forceinline__ float h_log2kap(int h) {
  float kap = (1.0f - exp2f(-5.0f - (float)h)) * 0.8f;
  return log2f(kap);
}
__device__ __forceinline__ float silu_f(float x) {
  return x / (1.0f + __expf(-x));
}
// async global->LDS, 16 bytes per lane; LDS base must be wave-uniform
__device__ __forceinline__ void gload_lds16(const half_t* g, half_t* l) {
  __builtin_amdgcn_global_load_lds(
      (const __attribute__((address_space(1))) unsigned int*)g,
      (__attribute__((address_space(3))) unsigned int*)l, 16, 0, 0);
}

// -- prep: weight convert+transpose (13 mats) + segment scan + x/obs -> fp16 --
// flat grid: [0,832) weight tiles; [832,836) seg scan; [836,1860) x/obs convert
struct WCArgs {
  const float* src[13];
  half_t* dst;
  const int* dones;
  int* seg;
  const float* x;
  const float* obs;
  half_t* hx;
  half_t* hobs;
};
__global__ __launch_bounds__(256) void prep_kernel(WCArgs a) {
  __shared__ half_t T[64][72];  // [k][n] tile, padded
  __shared__ int s[NS];
  const int t = threadIdx.x;
  const int id = blockIdx.x;
  if (id < 832) {
    const int w = id >> 6;
    const int tile = id & 63;
    const int kt = (tile & 7) * 64;
    const int nt = (tile >> 3) * 64;
    const float* src = a.src[w] + (size_t)kt * NE + nt;
    // float4 reads: 4 rounds x (16 rows x 64 cols)
    const int c4 = (t & 15) * 4;
    const int r0 = t >> 4;
#pragma unroll
    for (int rnd = 0; rnd < 4; rnd++) {
      int r = r0 + rnd * 16;
      float4 v = *(const float4*)(src + (size_t)r * NE + c4);
      T[r][c4 + 0] = (half_t)v.x;
      T[r][c4 + 1] = (half_t)v.y;
      T[r][c4 + 2] = (half_t)v.z;
      T[r][c4 + 3] = (half_t)v.w;
    }
    __syncthreads();
    const int n = t >> 2, kq = (t & 3) * 16;
    half_t* dst = a.dst + (size_t)w * NE * NE + (size_t)(nt + n) * NE + kt + kq;
    f16x8 o0, o1;
#pragma unroll
    for (int j = 0; j < 8; j++) {
      o0[j] = T[kq + j][n];
      o1[j] = T[kq + 8 + j][n];
    }
    *(f16x8*)dst = o0;
    *(f16x8*)(dst + 8) = o1;
  } else if (id < 836) {
    const int b = id - 832;
    for (int i = t; i < NS; i += 256) s[i] = (a.dones[b * NS + i] != 0) ? 1 : 0;
    __syncthreads();
    for (int off = 1; off < NS; off <<= 1) {
      int tv[4];
#pragma unroll
      for (int u = 0; u < 4; u++) {
        int i = t + 256 * u;
        tv[u] = s[i] + ((i >= off) ? s[i - off] : 0);
      }
      __syncthreads();
#pragma unroll
      for (int u = 0; u < 4; u++) s[t + 256 * u] = tv[u];
      __syncthreads();
    }
    for (int i = t; i < NS; i += 256) a.seg[b * NS + i] = s[i];
  } else {
    size_t i = ((size_t)(id - 836) * 256 + t) * 8;
    float4 v0 = *(const float4*)&a.x[i];
    float4 v1 = *(const float4*)&a.x[i + 4];
    f16x8 h;
    h[0] = (half_t)v0.x; h[1] = (half_t)v0.y; h[2] = (half_t)v0.z; h[3] = (half_t)v0.w;
    h[4] = (half_t)v1.x; h[5] = (half_t)v1.y; h[6] = (half_t)v1.z; h[7] = (half_t)v1.w;
    *(f16x8*)&a.hx[i] = h;
    float4 w0 = *(const float4*)&a.obs[i];
    float4 w1 = *(const float4*)&a.obs[i + 4];
    f16x8 g;
    g[0] = (half_t)w0.x; g[1] = (half_t)w0.y; g[2] = (half_t)w0.z; g[3] = (half_t)w0.w;
    g[4] = (half_t)w1.x; g[5] = (half_t)w1.y; g[6] = (half_t)w1.z; g[7] = (half_t)w1.w;
    *(f16x8*)&a.hobs[i] = g;
  }
}

// ---- fp16 MFMA GEMM (m97-style): O[w] = f(A[w]) @ Wt[w]^T * alpha[w], fp16 out
// Tile TM x 128, BK=64 halfs, 4 waves. TM=128: waves 2x2, 4x4 frags.
// TM=64: waves 2x2 over (32 x 64), 2x4 frags (for small grids -> 2x block count).
// A/B staged via global_load_lds width=16; LDS rows 128B, octet swizzle
// p = o ^ (row&7) -> bank load balanced at the structural floor.
// amode: 0 = A fp16 (async path); 3 = silu(A)*A2 elementwise (VGPR staging).
struct GArgs {
  const half_t *A0, *A1, *A2i, *A3;
  const half_t *B0, *B1, *B2, *B3;   // second operand for amode 3
  const half_t *W0, *W1, *W2, *W3;
  half_t *O0, *O1, *O2, *O3;
  float a0, a1, a2, a3;
  int am0, am1, am2, am3;
};

template <int TM>
__global__ __launch_bounds__(256) void mfma_gemm_kernel(GArgs g) {
  constexpr int MF = TM / 32;        // m-frags per wave (4 or 2)
  constexpr int AR = TM / 32;        // A staging rounds (4 or 2)
  __shared__ half_t As[TM * 64];
  __shared__ half_t Bs[128 * 64];
  const int t = threadIdx.x;
  const int bn = blockIdx.x;
  const int wsel = bn >> 2;
  const int n0 = (bn & 3) * 128;
  const int m0 = blockIdx.y * TM;
  const half_t* A = wsel == 0 ? g.A0 : wsel == 1 ? g.A1 : wsel == 2 ? g.A2i : g.A3;
  const half_t* A2 = wsel == 0 ? g.B0 : wsel == 1 ? g.B1 : wsel == 2 ? g.B2 : g.B3;
  const half_t* W = wsel == 0 ? g.W0 : wsel == 1 ? g.W1 : wsel == 2 ? g.W2 : g.W3;
  half_t* O = wsel == 0 ? g.O0 : wsel == 1 ? g.O1 : wsel == 2 ? g.O2 : g.O3;
  const float alpha = wsel == 0 ? g.a0 : wsel == 1 ? g.a1 : wsel == 2 ? g.a2 : g.a3;
  const int am = wsel == 0 ? g.am0 : wsel == 1 ? g.am1 : wsel == 2 ? g.am2 : g.am3;
  const int lane = t & 63;
  const int wv = t >> 6;
  const int frow = lane & 15;
  const int fo = lane >> 4;
  const int mbase = (wv & 1) * (TM / 2);
  const int nbase = (wv >> 1) * 64;

  f32x4 acc[MF][4];
#pragma unroll
  for (int i = 0; i < MF; i++)
#pragma unroll
    for (int j = 0; j < 4; j++) acc[i][j] = (f32x4){0.f, 0.f, 0.f, 0.f};

  // fragment LDS offsets (halfs): row*64 + (oct ^ (row&7))*8, oct = ks*4+fo
  int offA[2][MF], offB[2][4];
#pragma unroll
  for (int ks = 0; ks < 2; ks++) {
#pragma unroll
    for (int f = 0; f < MF; f++) {
      int ra = mbase + f * 16 + frow;
      offA[ks][f] = ra * 64 + (((ks * 4 + fo) ^ (ra & 7)) * 8);
    }
#pragma unroll
    for (int f = 0; f < 4; f++) {
      int rb = nbase + f * 16 + frow;
      offB[ks][f] = rb * 64 + (((ks * 4 + fo) ^ (rb & 7)) * 8);
    }
  }
  // staging: flat f = rnd*256 + t; row = f>>3, phys octet p = f&7,
  // source octet o = p ^ (row&7); dest halfs offset = f*8
  int srow[4], soct[4];
#pragma unroll
  for (int r = 0; r < 4; r++) {
    int f = r * 256 + t;
    srow[r] = f >> 3;
    soct[r] = (f & 7) ^ (srow[r] & 7);
  }
  const int ldsb = (t & 192) * 8;  // wave-uniform base (halfs) within a round

  for (int kt = 0; kt < NE; kt += 64) {
    if (am == 0) {
#pragma unroll
      for (int r = 0; r < AR; r++)
        gload_lds16(A + (size_t)(m0 + srow[r]) * NE + kt + soct[r] * 8,
                    &As[r * 2048 + ldsb]);
    } else {  // am == 3: silu(A)*A2
#pragma unroll
      for (int r = 0; r < AR; r++) {
        size_t gofs = (size_t)(m0 + srow[r]) * NE + kt + soct[r] * 8;
        f16x8 av = *(const f16x8*)(A + gofs);
        f16x8 bv = *(const f16x8*)(A2 + gofs);
        f16x8 ov;
#pragma unroll
        for (int e = 0; e < 8; e++)
          ov[e] = (half_t)(silu_f((float)av[e]) * (float)bv[e]);
        *(f16x8*)&As[(r * 256 + t) * 8] = ov;
      }
    }
#pragma unroll
    for (int r = 0; r < 4; r++)
      gload_lds16(W + (size_t)(n0 + srow[r]) * NE + kt + soct[r] * 8,
                  &Bs[r * 2048 + ldsb]);
    __syncthreads();
#pragma unroll
    for (int ks = 0; ks < 2; ks++) {
      f16x8 af[MF], bf[4];
#pragma unroll
      for (int f = 0; f < MF; f++) af[f] = *(const f16x8*)&As[offA[ks][f]];
#pragma unroll
      for (int f = 0; f < 4; f++) bf[f] = *(const f16x8*)&Bs[offB[ks][f]];
#pragma unroll
      for (int fm = 0; fm < MF; fm++)
#pragma unroll
        for (int fn = 0; fn < 4; fn++)
          acc[fm][fn] = __builtin_amdgcn_mfma_f32_16x16x32_f16(af[fm], bf[fn], acc[fm][fn], 0, 0, 0);
    }
    __syncthreads();
  }
  // epilogue: C/D layout col=lane&15, row=(lane>>4)*4+reg
#pragma unroll
  for (int fm = 0; fm < MF; fm++) {
    int rb = m0 + mbase + fm * 16 + fo * 4;
#pragma unroll
    for (int fn = 0; fn < 4; fn++) {
      int col = n0 + nbase + fn * 16 + frow;
#pragma unroll
      for (int r = 0; r < 4; r++)
        O[(size_t)(rb + r) * NE + col] = (half_t)(acc[fm][fn][r] * alpha);
    }
  }
}

// ------- retention pass 1 (MFMA): U_c[d][v] (fp16 out) + carry factor f ------
__global__ __launch_bounds__(256) void ret_pass1_kernel(
    const half_t* __restrict__ kmat, const half_t* __restrict__ vmat,
    const int* __restrict__ seg, const int* __restrict__ ts,
    half_t* __restrict__ U, float* __restrict__ fbuf) {
  __shared__ half_t KT[64 * 72];  // w-scaled K^T: [d][j]
  __shared__ half_t VT[64 * 72];  // V^T: [v][j]
  const int c = blockIdx.x, bh = blockIdx.y;
  const int b = bh >> 3, h = bh & 7;
  const float l2k = h_log2kap(h);
  const int t = threadIdx.x;
  const int r = t & 63, qd = t >> 6;
  const int e = c * CSZ + CSZ - 1;
  const int seg_e = seg[b * NS + e];
  const float ts_e = (float)ts[b * NS + e];
  {
    int gj = b * NS + c * CSZ + r;
    float w = (seg[gj] == seg_e) ? exp2f((ts_e - (float)ts[gj]) * l2k) : 0.0f;
    size_t gbase = (size_t)gj * NE + h * ND + qd * 16;
    f16x8 k0 = *(const f16x8*)&kmat[gbase];
    f16x8 k1 = *(const f16x8*)&kmat[gbase + 8];
    f16x8 v0 = *(const f16x8*)&vmat[gbase];
    f16x8 v1 = *(const f16x8*)&vmat[gbase + 8];
#pragma unroll
    for (int s = 0; s < 8; s++) {
      KT[(qd * 16 + s) * 72 + r] = (half_t)(w * (float)k0[s]);
      KT[(qd * 16 + 8 + s) * 72 + r] = (half_t)(w * (float)k1[s]);
      VT[(qd * 16 + s) * 72 + r] = v0[s];
      VT[(qd * 16 + 8 + s) * 72 + r] = v1[s];
    }
  }
  __syncthreads();
  const int lane = t & 63, wv = t >> 6;
  const int fr = lane & 15, fo8 = (lane >> 4) * 8;
  f32x4 acc[4];
#pragma unroll
  for (int j = 0; j < 4; j++) acc[j] = (f32x4){0.f, 0.f, 0.f, 0.f};
#pragma unroll
  for (int ks = 0; ks < 2; ks++) {
    f16x8 af = *(const f16x8*)&KT[(wv * 16 + fr) * 72 + ks * 32 + fo8];
#pragma unroll
    for (int nt = 0; nt < 4; nt++) {
      f16x8 bf = *(const f16x8*)&VT[(nt * 16 + fr) * 72 + ks * 32 + fo8];
      acc[nt] = __builtin_amdgcn_mfma_f32_16x16x32_f16(af, bf, acc[nt], 0, 0, 0);
    }
  }
  half_t* Uo = U + ((size_t)bh * NC + c) * (ND * ND);
  const int drow = wv * 16 + (lane >> 4) * 4;
#pragma unroll
  for (int nt = 0; nt < 4; nt++)
#pragma unroll
    for (int rg = 0; rg < 4; rg++)
      Uo[(drow + rg) * ND + nt * 16 + fr] = (half_t)acc[nt][rg];
  if (t == 0) {
    int ps = 0;
    float pt = -1.0f;
    if (c > 0) {
      ps = seg[b * NS + c * CSZ - 1];
      pt = (float)ts[b * NS + c * CSZ - 1];
    }
    fbuf[bh * NC + c] = (seg_e == ps) ? exp2f((ts_e - pt) * l2k) : 0.0f;
  }
}

// -- retention pass 2+3 fused: per-block P_c scan from fp16 U, then chunk work.
__global__ __launch_bounds__(256) void ret_pass23_kernel(
    const half_t* __restrict__ qmat, const half_t* __restrict__ kmat,
    const half_t* __restrict__ vmat, const half_t* __restrict__ U,
    const float* __restrict__ fbuf, const float* __restrict__ hin,
    float* __restrict__ hout, const half_t* __restrict__ gmat,
    const int* __restrict__ seg, const int* __restrict__ ts,
    const float* __restrict__ gns, const float* __restrict__ gnb,
    half_t* __restrict__ y16) {
  __shared__ half_t Qs[64 * 72];
  __shared__ half_t KS[64 * 72];
  __shared__ half_t VT[64 * 72];
  __shared__ half_t PT[64 * 72];
  __shared__ int segs[64];
  __shared__ int tss[64];
  __shared__ float gnsv[64];
  __shared__ float gnbv[64];
  const int c = blockIdx.x, bh = blockIdx.y;
  const int b = bh >> 3, h = bh & 7;
  const float l2k = h_log2kap(h);
  const int t = threadIdx.x;
  const int r = t & 63, qd = t >> 6;
  float pv[16];
  {
    float coef = 1.0f;
#pragma unroll
    for (int u = 0; u < 16; u++) pv[u] = 0.f;
    for (int cp = c - 1; cp >= 0; --cp) {
      const half_t* up = U + ((size_t)bh * NC + cp) * 4096 + r * 64 + qd * 16;
      f16x8 u0 = *(const f16x8*)up;
      f16x8 u1 = *(const f16x8*)(up + 8);
#pragma unroll
      for (int s = 0; s < 8; s++) {
        pv[s] += coef * (float)u0[s];
        pv[8 + s] += coef * (float)u1[s];
      }
      coef *= fbuf[bh * NC + cp];
    }
    const float* h0 = hin + (size_t)bh * 4096 + r * 64 + qd * 16;
    float hv[16];
    *(float4*)&hv[0] = *(const float4*)h0;
    *(float4*)&hv[4] = *(const float4*)(h0 + 4);
    *(float4*)&hv[8] = *(const float4*)(h0 + 8);
    *(float4*)&hv[12] = *(const float4*)(h0 + 12);
#pragma unroll
    for (int u = 0; u < 16; u++) pv[u] += coef * hv[u];
  }
  if (c == NC) {
    float* ho = hout + (size_t)bh * 4096 + r * 64 + qd * 16;
    *(float4*)ho = *(float4*)&pv[0];
    *(float4*)(ho + 4) = *(float4*)&pv[4];
    *(float4*)(ho + 8) = *(float4*)&pv[8];
    *(float4*)(ho + 12) = *(float4*)&pv[12];
    return;
  }
  {
    size_t gbase = (size_t)(b * NS + c * CSZ + r) * NE + h * ND + qd * 16;
    f16x8 q0 = *(const f16x8*)&qmat[gbase];
    f16x8 q1 = *(const f16x8*)&qmat[gbase + 8];
    *(f16x8*)&Qs[r * 72 + qd * 16] = q0;
    *(f16x8*)&Qs[r * 72 + qd * 16 + 8] = q1;
    f16x8 k0 = *(const f16x8*)&kmat[gbase];
    f16x8 k1 = *(const f16x8*)&kmat[gbase + 8];
    *(f16x8*)&KS[r * 72 + qd * 16] = k0;
    *(f16x8*)&KS[r * 72 + qd * 16 + 8] = k1;
    f16x8 v0 = *(const f16x8*)&vmat[gbase];
    f16x8 v1 = *(const f16x8*)&vmat[gbase + 8];
#pragma unroll
    for (int s = 0; s < 8; s++) {
      VT[(qd * 16 + s) * 72 + r] = v0[s];
      VT[(qd * 16 + 8 + s) * 72 + r] = v1[s];
      PT[(qd * 16 + s) * 72 + r] = (half_t)pv[s];
      PT[(qd * 16 + 8 + s) * 72 + r] = (half_t)pv[8 + s];
    }
    if (t < 64) {
      segs[t] = seg[b * NS + c * CSZ + t];
      tss[t] = ts[b * NS + c * CSZ + t];
    } else if (t < 128) {
      gnsv[t - 64] = gns[h * ND + t - 64];
      gnbv[t - 64] = gnb[h * ND + t - 64];
    }
  }
  __syncthreads();
  const int lane = t & 63, wv = t >> 6;
  const int fr = lane & 15, fo8 = (lane >> 4) * 8;
  f32x4 aq[4];
#pragma unroll
  for (int j = 0; j < 4; j++) aq[j] = (f32x4){0.f, 0.f, 0.f, 0.f};
#pragma unroll
  for (int ks = 0; ks < 2; ks++) {
    f16x8 af = *(const f16x8*)&Qs[(wv * 16 + fr) * 72 + ks * 32 + fo8];
#pragma unroll
    for (int nt = 0; nt < 4; nt++) {
      f16x8 bf = *(const f16x8*)&KS[(nt * 16 + fr) * 72 + ks * 32 + fo8];
      aq[nt] = __builtin_amdgcn_mfma_f32_16x16x32_f16(af, bf, aq[nt], 0, 0, 0);
    }
  }
  __syncthreads();
  const int qrow = wv * 16 + (lane >> 4) * 4;
#pragma unroll
  for (int nt = 0; nt < 4; nt++) {
    int j = nt * 16 + fr;
    int sj = segs[j];
    float tsj = (float)tss[j];
#pragma unroll
    for (int rg = 0; rg < 4; rg++) {
      int i = qrow + rg;
      float w = 0.0f;
      if (j <= i && sj == segs[i]) w = exp2f(((float)tss[i] - tsj) * l2k);
      KS[i * 72 + j] = (half_t)(aq[nt][rg] * w);
    }
  }
  __syncthreads();
  float gi;
  {
    int ps = 0;
    float pt = -1.0f;
    if (c > 0) {
      ps = seg[b * NS + c * CSZ - 1];
      pt = (float)ts[b * NS + c * CSZ - 1];
    }
    int i = wv * 16 + fr;
    gi = (segs[i] == ps) ? exp2f(((float)tss[i] - pt) * l2k) : 0.0f;
  }
  f32x4 acc[4];
#pragma unroll
  for (int j = 0; j < 4; j++) acc[j] = (f32x4){0.f, 0.f, 0.f, 0.f};
#pragma unroll
  for (int ks = 0; ks < 2; ks++) {
    f16x8 saf = *(const f16x8*)&KS[(wv * 16 + fr) * 72 + ks * 32 + fo8];
    f16x8 qaf = *(const f16x8*)&Qs[(wv * 16 + fr) * 72 + ks * 32 + fo8];
    f16x8 gqf;
#pragma unroll
    for (int e = 0; e < 8; e++) gqf[e] = (half_t)(gi * (float)qaf[e]);
#pragma unroll
    for (int nt = 0; nt < 4; nt++) {
      f16x8 vbf = *(const f16x8*)&VT[(nt * 16 + fr) * 72 + ks * 32 + fo8];
      acc[nt] = __builtin_amdgcn_mfma_f32_16x16x32_f16(saf, vbf, acc[nt], 0, 0, 0);
      f16x8 pbf = *(const f16x8*)&PT[(nt * 16 + fr) * 72 + ks * 32 + fo8];
      acc[nt] = __builtin_amdgcn_mfma_f32_16x16x32_f16(gqf, pbf, acc[nt], 0, 0, 0);
    }
  }
#pragma unroll
  for (int rg = 0; rg < 4; rg++) {
    float s1 = acc[0][rg] + acc[1][rg] + acc[2][rg] + acc[3][rg];
    float s2 = acc[0][rg] * acc[0][rg] + acc[1][rg] * acc[1][rg] +
               acc[2][rg] * acc[2][rg] + acc[3][rg] * acc[3][rg];
    s1 += __shfl_xor(s1, 1); s2 += __shfl_xor(s2, 1);
    s1 += __shfl_xor(s1, 2); s2 += __shfl_xor(s2, 2);
    s1 += __shfl_xor(s1, 4); s2 += __shfl_xor(s2, 4);
    s1 += __shfl_xor(s1, 8); s2 += __shfl_xor(s2, 8);
    float mu = s1 * (1.0f / 64.0f);
    float var = s2 * (1.0f / 64.0f) - mu * mu;
    float rs = rsqrtf(var + FEPS);
    int i = qrow + rg;
    size_t ybase = (size_t)(b * NS + c * CSZ + i) * NE + h * ND;
#pragma unroll
    for (int nt = 0; nt < 4; nt++) {
      int col = nt * 16 + fr;
      float gg = (float)gmat[ybase + col];
      float val = (acc[nt][rg] - mu) * rs * gnsv[col] + gnbv[col];
      y16[ybase + col] = (half_t)(silu_f(gg) * val);
    }
  }
}

// -- residual RMS norm; OMODE 0: fp32 out, 1: fp16 out, 2: both. a is fp16. ---
template <int OMODE>
__global__ __launch_bounds__(256) void rms_kernel(const half_t* __restrict__ a,
                                                  const float* __restrict__ res,
                                                  const float* __restrict__ scale,
                                                  float* __restrict__ outf,
                                                  half_t* __restrict__ outh) {
  int row = blockIdx.x * 4 + (threadIdx.x >> 6);
  int lane = threadIdx.x & 63;
  int base = row * NE + lane * 8;
  f16x8 ah = *(const f16x8*)&a[base];
  float x[8], r[8];
  *(float4*)&r[0] = *(const float4*)&res[base];
  *(float4*)&r[4] = *(const float4*)&res[base + 4];
  float ss = 0.f;
#pragma unroll
  for (int u = 0; u < 8; u++) {
    x[u] = (float)ah[u] + r[u];
    ss += x[u] * x[u];
  }
#pragma unroll
  for (int off = 1; off < 64; off <<= 1) ss += __shfl_xor(ss, off);
  float rsf = rsqrtf(ss * (1.0f / 512.0f) + FEPS);
  float s[8];
  *(float4*)&s[0] = *(const float4*)&scale[lane * 8];
  *(float4*)&s[4] = *(const float4*)&scale[lane * 8 + 4];
  float o[8];
#pragma unroll
  for (int u = 0; u < 8; u++) o[u] = x[u] * rsf * s[u];
  if (OMODE == 0 || OMODE == 2) {
    *(float4*)&outf[base] = *(float4*)&o[0];
    *(float4*)&outf[base + 4] = *(float4*)&o[4];
  }
  if (OMODE == 1 || OMODE == 2) {
    f16x8 h;
#pragma unroll
    for (int u = 0; u < 8; u++) h[u] = (half_t)o[u];
    *(f16x8*)&outh[base] = h;
  }
}

extern "C" void kernel_launch(void* const* d_in, const int* in_sizes, int n_in,
                              void* d_out, int out_size, void* d_ws, size_t ws_size,
                              hipStream_t stream) {
  (void)in_sizes; (void)n_in; (void)out_size; (void)ws_size;
  const float* x = (const float*)d_in[0];
  const float* obs = (const float*)d_in[1];
  const float* hs1 = (const float*)d_in[2];
  const float* hs2 = (const float*)d_in[3];
  const int* dones = (const int*)d_in[4];
  const int* tsid = (const int*)d_in[5];
  const float* ln1 = (const float*)d_in[6];
  const float* ln2 = (const float*)d_in[7];
  const float* ln3 = (const float*)d_in[8];
  const float* r1_gs = (const float*)d_in[14];
  const float* r1_gb = (const float*)d_in[15];
  const float* r2_gs = (const float*)d_in[21];
  const float* r2_gb = (const float*)d_in[22];

  const size_t NBUF = (size_t)NB * NS * NE;  // 2,097,152 elements
  char* ws = (char*)d_ws;
  int* segb = (int*)ws;                              // 16 KB
  float* fb = (float*)(ws + 16384);                  // 2 KB
  half_t* W16 = (half_t*)(ws + 18432);               // 13 x 512 KB
  char* p = ws + 18432 + (size_t)13 * NE * NE * sizeof(half_t);
  float* F1 = (float*)p;                 // y (fp32 residual for final rms)
  half_t* Uh = (half_t*)(F1 + NBUF);     // U (fp16)
  half_t* Hq = Uh + NBUF;
  half_t* Hk = Hq + NBUF;
  half_t* Hv = Hk + NBUF;
  half_t* Hg = Hv + NBUF;
  half_t* H1 = Hg + NBUF;                // pass3 output (gated, fp16)
  half_t* H2 = H1 + NBUF;                // rms fp16 output
  half_t* H3 = H2 + NBUF;                // wo/ffn GEMM fp16 outputs
  half_t* Hx = H3 + NBUF;                // x fp16
  half_t* Hobs = Hx + NBUF;              // obs fp16

  float* out = (float*)d_out;
  float* hs1o = out + NBUF;
  float* hs2o = hs1o + (size_t)NB * NH * ND * ND;

  WCArgs wc;
  wc.src[0] = (const float*)d_in[9];   wc.src[1] = (const float*)d_in[10];
  wc.src[2] = (const float*)d_in[11];  wc.src[3] = (const float*)d_in[12];
  wc.src[4] = (const float*)d_in[13];  wc.src[5] = (const float*)d_in[16];
  wc.src[6] = (const float*)d_in[17];  wc.src[7] = (const float*)d_in[18];
  wc.src[8] = (const float*)d_in[19];  wc.src[9] = (const float*)d_in[20];
  wc.src[10] = (const float*)d_in[24]; wc.src[11] = (const float*)d_in[23];
  wc.src[12] = (const float*)d_in[25];
  wc.dst = W16;
  wc.dones = dones;
  wc.seg = segb;
  wc.x = x; wc.obs = obs; wc.hx = Hx; wc.hobs = Hobs;
  const half_t* WS[13];
  for (int i = 0; i < 13; i++) WS[i] = W16 + (size_t)i * NE * NE;

  dim3 gR(16, 32), gR23(17, 32);

  prep_kernel<<<1860, 256, 0, stream>>>(wc);

  // ---- retention layer 1: q,k,v,g = x16 @ {wq,wk,wv,wg} ----
  {
    GArgs a = {Hx, Hx, Hx, Hx, nullptr, nullptr, nullptr, nullptr,
               WS[0], WS[1], WS[2], WS[3], Hq, Hk, Hv, Hg,
               1.0f, 0.125f, 1.0f, 1.0f, 0, 0, 0, 0};
    mfma_gemm_kernel<128><<<dim3(16, 32), 256, 0, stream>>>(a);
  }
  ret_pass1_kernel<<<gR, 256, 0, stream>>>(Hk, Hv, segb, tsid, Uh, fb);
  ret_pass23_kernel<<<gR23, 256, 0, stream>>>(Hq, Hk, Hv, Uh, fb, hs1, hs1o,
                                              Hg, segb, tsid, r1_gs, r1_gb, H1);
  {  // o1 = H1 @ wo -> H3 (fp16); TM=64 -> 256 blocks
    GArgs a = {H1, H1, H1, H1, nullptr, nullptr, nullptr, nullptr,
               WS[4], WS[4], WS[4], WS[4], H3, H3, H3, H3,
               1.0f, 1.0f, 1.0f, 1.0f, 0, 0, 0, 0};
    mfma_gemm_kernel<64><<<dim3(4, 64), 256, 0, stream>>>(a);
  }
  rms_kernel<1><<<1024, 256, 0, stream>>>(H3, x, ln1, nullptr, H2);  // x2 -> H2

  // ---- retention layer 2: q2,g2 = obs16@{wq,wg}; k2,v2 = x2@{wk,wv} ----
  {
    GArgs a = {Hobs, Hobs, H2, H2, nullptr, nullptr, nullptr, nullptr,
               WS[5], WS[8], WS[6], WS[7], Hq, Hg, Hk, Hv,
               1.0f, 1.0f, 0.125f, 1.0f, 0, 0, 0, 0};
    mfma_gemm_kernel<128><<<dim3(16, 32), 256, 0, stream>>>(a);
  }
  ret_pass1_kernel<<<gR, 256, 0, stream>>>(Hk, Hv, segb, tsid, Uh, fb);
  ret_pass23_kernel<<<gR23, 256, 0, stream>>>(Hq, Hk, Hv, Uh, fb, hs2, hs2o,
                                              Hg, segb, tsid, r2_gs, r2_gb, H1);
  {  // o2 = H1 @ wo -> H3; TM=64 -> 256 blocks
    GArgs a = {H1, H1, H1, H1, nullptr, nullptr, nullptr, nullptr,
               WS[9], WS[9], WS[9], WS[9], H3, H3, H3, H3,
               1.0f, 1.0f, 1.0f, 1.0f, 0, 0, 0, 0};
    mfma_gemm_kernel<64><<<dim3(4, 64), 256, 0, stream>>>(a);
  }
  rms_kernel<2><<<1024, 256, 0, stream>>>(H3, obs, ln2, F1, H2);  // y -> F1 + H2

  // ---- FFN: wg,wl from H2 -> Hq,Hk (fp16); TM=64 -> 512 blocks ----
  {
    GArgs a = {H2, H2, H2, H2, nullptr, nullptr, nullptr, nullptr,
               WS[10], WS[11], WS[10], WS[11], Hq, Hk, Hq, Hk,
               1.0f, 1.0f, 1.0f, 1.0f, 0, 0, 0, 0};
    mfma_gemm_kernel<64><<<dim3(8, 64), 256, 0, stream>>>(a);
  }
  {  // ffn = (silu(Hq) * Hk) @ wo -> H3; TM=64 -> 256 blocks
    GArgs a = {Hq, Hq, Hq, Hq, Hk, Hk, Hk, Hk,
               WS[12], WS[12], WS[12], WS[12], H3, H3, H3, H3,
               1.0f, 1.0f, 1.0f, 1.0f, 3, 3, 3, 3};
    mfma_gemm_kernel<64><<<dim3(4, 64), 256, 0, stream>>>(a);
  }
  rms_kernel<0><<<1024, 256, 0, stream>>>(H3, F1, ln3, out, nullptr);
}